// Round 17
// baseline (44.044 us; speedup 1.0000x reference)
//
#include <hip/hip_runtime.h>
#include <hip/hip_bf16.h>
#include <math.h>

typedef __attribute__((ext_vector_type(8))) short bf16x8;
typedef __attribute__((ext_vector_type(4))) float f32x4;

#define T_TOT 16384
#define E_ 256
#define FF_ 1024
#define NQ 10
#define CH 128                  // f per chunk (4 kk, 8 f-tiles)
#define NCHUNK (FF_ / CH)       // 8
#define HG (64 * CH)            // shorts per wave's hs slab (8192 = 16 KiB)

// paired f32->bf16 RNE via v_cvt_pk_bf16_f32
__device__ __forceinline__ unsigned pkbf(float a, float b) {
    __hip_bfloat162 t = __float22bfloat162_rn(make_float2(a, b));
    return *(unsigned*)&t;
}

// ---------------------------------------------------------------------------
// Prep (coalesced): bf16 MFMA B-fragments for w2 and w1^T.  (unchanged)
// ---------------------------------------------------------------------------
__global__ __launch_bounds__(256) void ffq_prep(
    const float* __restrict__ w2, const float* __restrict__ w1,
    uint4* __restrict__ w2f, uint4* __restrict__ w1f)
{
    int id = blockIdx.x * 256 + threadIdx.x;
    if (id < 32768) {
        int n  = id >> 7;
        int k0 = (id & 127) * 8;
        const float4* s = (const float4*)(w2 + (size_t)n * FF_ + k0);
        float4 a = s[0], b = s[1];
        uint4 v;
        v.x = pkbf(a.x, a.y);
        v.y = pkbf(a.z, a.w);
        v.z = pkbf(b.x, b.y);
        v.w = pkbf(b.z, b.w);
        int idx = ((k0 >> 5) * 16 + (n >> 4)) * 64 + ((k0 >> 3) & 3) * 16 + (n & 15);
        w2f[idx] = v;
    } else if (id < 32768 + 4096) {
        int id2 = id - 32768;
        int l = id2 & 63, nt = id2 >> 6;
        int n = nt * 16 + (l & 15);
        int g = l >> 4;
        float o[8];
#pragma unroll
        for (int j = 0; j < 8; ++j) {
            int k = g * 8 + j;
            o[j] = (k < NQ) ? w1[n * NQ + k] : 0.f;
        }
        uint4 v;
        v.x = pkbf(o[0], o[1]);
        v.y = pkbf(o[2], o[3]);
        v.z = pkbf(o[4], o[5]);
        v.w = pkbf(o[6], o[7]);
        w1f[id2] = v;
    }
}

// ---------------------------------------------------------------------------
// Fused kernel v17 (wave-autonomous, ZERO barriers):
//  - 2048 independent waves; each owns 64 tokens x 32 cols end-to-end.
//  - q computed in-register per wave (no q LDS, no phase-0 barrier).
//  - h written to a PRIVATE 16 KiB LDS slab in A-fragment layout (verified
//    granule formulas); within-wave RAW ordered by lgkmcnt, no barrier.
//  - out-phase: A ds_read_b128 + B depth-1 global prefetch + 8 MFMA per kk.
//  - h computed 8x redundantly across col-groups (MFMA is cheap/idle).
//  - 512 blocks x 256 thr; LDS 64 KiB -> 2 blocks/CU; no __syncthreads.
// ---------------------------------------------------------------------------
__global__ __launch_bounds__(256, 2) void ffq_mfma(
    const float* __restrict__ x, const float* __restrict__ theta,
    const float* __restrict__ b1, const float* __restrict__ b2,
    const bf16x8* __restrict__ w1f, const bf16x8* __restrict__ w2f,
    float* __restrict__ out)
{
    __shared__ unsigned short hs[4 * HG];    // 64 KiB: one 16 KiB slab/wave

    const int tid  = threadIdx.x;
    const int l    = tid & 63;
    const int wv   = tid >> 6;               // 0..3
    const int lr   = l & 15;
    const int g    = l >> 4;                 // 0..3
    const int wid  = blockIdx.x * 4 + wv;    // 0..2047
    const int tb   = (wid >> 3) * 64;        // 64-token stripe
    const int nc0  = (wid & 7) * 2;          // wave's col-tiles (32 cols)
    const int nc1  = nc0 + 1;

    unsigned short* hsw = hs + wv * HG;      // private slab

    // ---- q in registers: lane computes q for tokens tb + tt*16 + lr ----
    float ct[NQ];
#pragma unroll
    for (int w = 0; w < NQ; ++w) ct[w] = cosf(theta[w]);

    bf16x8 qf[4];
#pragma unroll
    for (int tt = 0; tt < 4; ++tt) {
        const int t = tb + tt * 16 + lr;
        float xv[NQ];
        {
            float4 a = *(const float4*)(x + (size_t)t * E_);
            float4 b = *(const float4*)(x + (size_t)t * E_ + 4);
            float2 c = *(const float2*)(x + (size_t)t * E_ + 8);
            xv[0]=a.x; xv[1]=a.y; xv[2]=a.z; xv[3]=a.w;
            xv[4]=b.x; xv[5]=b.y; xv[6]=b.z; xv[7]=b.w;
            xv[8]=c.x; xv[9]=c.y;
        }
        float mm[NQ], qv[NQ];
#pragma unroll
        for (int w = 0; w < NQ; ++w) mm[w] = ct[w] * cosf(xv[w]);
        {
            float p = mm[0];
#pragma unroll
            for (int w = 1; w < NQ; ++w) { p *= mm[w]; qv[w] = p; }
            float p0 = mm[1];
#pragma unroll
            for (int w = 2; w < NQ; ++w) p0 *= mm[w];
            qv[0] = p0;
        }
        uint4 v;
#pragma unroll
        for (int h2 = 0; h2 < 4; ++h2) {
            int k0 = g * 8 + h2 * 2;
            float a0 = (k0     < NQ) ? qv[k0]     : 0.f;
            float a1 = (k0 + 1 < NQ) ? qv[k0 + 1] : 0.f;
            ((unsigned*)&v)[h2] = pkbf(a0, a1);
        }
        qf[tt] = __builtin_bit_cast(bf16x8, v);
    }

    f32x4 acc[4][2];
#pragma unroll
    for (int tt = 0; tt < 4; ++tt)
#pragma unroll
        for (int nn = 0; nn < 2; ++nn) acc[tt][nn] = (f32x4){0.f,0.f,0.f,0.f};

    // B prefetch for kk=0
    bf16x8 bc0 = w2f[(0 * 16 + nc0) * 64 + l];
    bf16x8 bc1 = w2f[(0 * 16 + nc1) * 64 + l];
    // w1 rolling prefetch
    bf16x8 wfc = w1f[0 * 64 + l];

    for (int c = 0; c < NCHUNK; ++c) {
        // ---- h-phase: 8 f-tiles into the private slab (verified layout) ----
#pragma unroll
        for (int nt = 0; nt < 8; ++nt) {
            const int ntg = c * 8 + nt;
            bf16x8 wfn = (ntg + 1 < 64) ? w1f[(ntg + 1) * 64 + l] : wfc;
            f32x4  bbc = *(const f32x4*)(b1 + ntg * 16 + g * 4);
            const int fl  = nt * 16 + g * 4;      // f local in chunk
            const int kkl = fl >> 5;
            const int sl  = (fl & 31) >> 3;
            const int sub = (fl & 7) * 2;
#pragma unroll
            for (int tt = 0; tt < 4; ++tt) {
                f32x4 d = __builtin_amdgcn_mfma_f32_16x16x32_bf16(
                        wfc, qf[tt], bbc, 0, 0, 0);
                unsigned p0 = pkbf(fmaxf(d[0], 0.f), fmaxf(d[1], 0.f));
                unsigned p1 = pkbf(fmaxf(d[2], 0.f), fmaxf(d[3], 0.f));
                unsigned byteoff = (unsigned)((tt * 4 + kkl) * 64 + lr
                                   + 16 * sl) * 16u + (unsigned)sub;
                *(uint2*)((char*)hsw + byteoff) = make_uint2(p0, p1);
            }
            wfc = wfn;
        }

        // ---- out-phase: 4 kk steps from the slab (lgkmcnt-ordered) ----
        const bf16x8* hc = (const bf16x8*)hsw;
#pragma unroll
        for (int kkl = 0; kkl < 4; ++kkl) {
            const int kk  = c * 4 + kkl;
            const int kkn = (kk + 1 < 32) ? kk + 1 : 31;
            bf16x8 bn0 = w2f[(kkn * 16 + nc0) * 64 + l];
            bf16x8 bn1 = w2f[(kkn * 16 + nc1) * 64 + l];
            bf16x8 af[4];
#pragma unroll
            for (int tt = 0; tt < 4; ++tt)
                af[tt] = hc[(tt * 4 + kkl) * 64 + l];
            __builtin_amdgcn_s_setprio(1);
#pragma unroll
            for (int tt = 0; tt < 4; ++tt)
                acc[tt][0] = __builtin_amdgcn_mfma_f32_16x16x32_bf16(
                    af[tt], bc0, acc[tt][0], 0, 0, 0);
#pragma unroll
            for (int tt = 0; tt < 4; ++tt)
                acc[tt][1] = __builtin_amdgcn_mfma_f32_16x16x32_bf16(
                    af[tt], bc1, acc[tt][1], 0, 0, 0);
            __builtin_amdgcn_s_setprio(0);
            bc0 = bn0; bc1 = bn1;
        }
    }

    // ---- epilogue: + b2, store fp32 ----
#pragma unroll
    for (int nn = 0; nn < 2; ++nn) {
        const int col = (nc0 + nn) * 16 + lr;
        const float bbv = b2[col];
#pragma unroll
        for (int tt = 0; tt < 4; ++tt) {
#pragma unroll
            for (int r = 0; r < 4; ++r) {
                int tr = tb + tt * 16 + g * 4 + r;
                out[(size_t)tr * E_ + col] = acc[tt][nn][r] + bbv;
            }
        }
    }
}

extern "C" void kernel_launch(void* const* d_in, const int* in_sizes, int n_in,
                              void* d_out, int out_size, void* d_ws, size_t ws_size,
                              hipStream_t stream) {
    const float* x     = (const float*)d_in[0];
    const float* theta = (const float*)d_in[1];
    const float* w1    = (const float*)d_in[2];
    const float* b1    = (const float*)d_in[3];
    const float* w2    = (const float*)d_in[4];
    const float* b2    = (const float*)d_in[5];
    float* out = (float*)d_out;

    uint4* w2f = (uint4*)d_ws;                          // 512 KiB
    uint4* w1f = (uint4*)((char*)d_ws + 512 * 1024);    // 64 KiB

    hipLaunchKernelGGL(ffq_prep, dim3(144), dim3(256), 0, stream,
                       w2, w1, w2f, w1f);
    hipLaunchKernelGGL(ffq_mfma, dim3(512), dim3(256), 0, stream,
                       x, theta, b1, b2,
                       (const bf16x8*)w1f, (const bf16x8*)w2f, out);
}